// Round 3
// baseline (10744.088 us; speedup 1.0000x reference)
//
#include <hip/hip_runtime.h>

typedef __attribute__((ext_vector_type(8))) short short8;
typedef __attribute__((ext_vector_type(4))) float f32x4;

#define NROWS 4096     // B*L = 32*128
#define CC    192
#define NCEL  (NROWS * CC)
#define WELEM (3 * 576 * 192)   // 331776 per half

// ---------- numerics helpers ----------
__device__ __forceinline__ unsigned short f2bf(float x) {
    union { float f; unsigned int u; } v; v.f = x;
    unsigned int r = v.u + 0x7fffu + ((v.u >> 16) & 1u);   // RNE
    return (unsigned short)(r >> 16);
}
__device__ __forceinline__ float bf2f(unsigned short h) {
    union { unsigned int u; float f; } v; v.u = ((unsigned int)h) << 16;
    return v.f;
}
__device__ __forceinline__ unsigned packhl(float x) {
    unsigned short h = f2bf(x);
    unsigned short l = f2bf(x - bf2f(h));
    return (unsigned)h | ((unsigned)l << 16);
}
__device__ __forceinline__ float sigmoid_f(float x) {
    return 1.0f / (1.0f + __expf(-x));
}
__device__ __forceinline__ float tanh_f(float x) {
    float ax = fabsf(x);
    if (ax < 0.0625f) {
        float x2 = x * x;
        return x * fmaf(x2, fmaf(x2, 0.13333333f, -0.33333333f), 1.0f);
    }
    float e = __expf(2.0f * fminf(ax, 20.0f));
    float t = (e - 1.0f) / (e + 1.0f);
    return x < 0.0f ? -t : t;
}

// ---------- prep ----------
__global__ void prep_x(const float* __restrict__ x, unsigned* __restrict__ memHL) {
    int i = blockIdx.x * 256 + threadIdx.x;
    if (i < NCEL) memHL[i] = packhl(x[i]);
}

// input w: [kk][ci][co] flat = kglob*192+co.  output: [conv][ch 18][ksl 4][co 192][8]
__global__ void prep_w(const float* __restrict__ wr, const float* __restrict__ wg,
                       const float* __restrict__ wc,
                       unsigned short* __restrict__ W2H, unsigned short* __restrict__ W2L) {
    int i = blockIdx.x * 256 + threadIdx.x;
    if (i >= WELEM) return;
    int conv = i / 110592;
    int rem  = i - conv * 110592;
    int kglob = rem / 192;
    int co    = rem - kglob * 192;
    const float* w = (conv == 0) ? wr : ((conv == 1) ? wg : wc);
    float v = w[(size_t)kglob * 192 + co];
    int ch  = kglob >> 5;
    int klo = kglob & 31;
    int ksl = klo >> 3;
    int e   = klo & 7;
    size_t dst = ((size_t)((conv * 18 + ch) * 4 + ksl)) * 1536 + co * 8 + e;
    unsigned short h = f2bf(v);
    unsigned short l = f2bf(v - bf2f(h));
    W2H[dst] = h; W2L[dst] = l;
}

// ---------- grid barrier (relaxed atomics; data via agent-scope sc1 ops) ----------
__device__ __forceinline__ void gridbar(unsigned* flags, int bid, int tid, unsigned ep) {
    __syncthreads();   // drains vmcnt(0): all our agent-scope stores are at L3
    if (tid == 0)
        __hip_atomic_store(&flags[bid], ep, __ATOMIC_RELAXED, __HIP_MEMORY_SCOPE_AGENT);
    while (__hip_atomic_load(&flags[tid], __ATOMIC_RELAXED, __HIP_MEMORY_SCOPE_AGENT) < ep)
        __builtin_amdgcn_s_sleep(1);
    __syncthreads();
}

// stage 34 rows (n0-1 .. n0+32) of a packed h|l<<16 array into AH/AL (swizzled)
#define STAGE(SRC) do {                                                              \
    _Pragma("unroll")                                                                \
    for (int it_ = 0; it_ < 13; ++it_) {                                             \
        int q_ = it_ * 256 + tid;                                                    \
        if (q_ < 3264) {                                                             \
            int row_ = q_ / 96; int pr_ = q_ - row_ * 96;                            \
            int gr_ = n0 - 1 + row_;                                                 \
            unsigned long long v_ = 0ull;                                            \
            if (gr_ >= 0 && ((gr_ >> 7) == (n0 >> 7)))                               \
                v_ = __hip_atomic_load(((const unsigned long long*)(SRC)) +          \
                        ((size_t)gr_ * 96 + pr_), __ATOMIC_RELAXED,                  \
                        __HIP_MEMORY_SCOPE_AGENT);                                   \
            unsigned lo_ = (unsigned)v_, hi_ = (unsigned)(v_ >> 32);                 \
            unsigned byt_ = ((unsigned)(pr_ * 4)) ^ (((unsigned)(row_ & 7)) << 4);   \
            unsigned wdx_ = (((unsigned)row_) * 384 + byt_) >> 2;                    \
            ((unsigned*)AH)[wdx_] = (lo_ & 0xFFFFu) | ((hi_ & 0xFFFFu) << 16);       \
            ((unsigned*)AL)[wdx_] = (lo_ >> 16) | ((hi_ >> 16) << 16);               \
        }                                                                            \
    }                                                                                \
} while (0)

#define LDB(CH, BH, BL) do {                                                         \
    BH[0] = *(const short8*)(WH + (CH) * 6144 + bc0);                                \
    BH[1] = *(const short8*)(WH + (CH) * 6144 + bc1);                                \
    BH[2] = *(const short8*)(WH + (CH) * 6144 + bc2);                                \
    BL[0] = *(const short8*)(WL + (CH) * 6144 + bc0);                                \
    BL[1] = *(const short8*)(WL + (CH) * 6144 + bc1);                                \
    BL[2] = *(const short8*)(WL + (CH) * 6144 + bc2);                                \
} while (0)

#define CMP(CH, BH, BL) do {                                                         \
    const int kk_ = (CH) / 6, ci0_ = ((CH) % 6) * 32;                                \
    const int cb2_ = ci0_ * 2 + (ksl << 4);                                          \
    const int tr0_ = lrow + kk_;                                                     \
    const int tr1_ = tr0_ + 16;                                                      \
    const short8 a0h = *(const short8*)(AH + tr0_ * 192 +                            \
        ((((unsigned)cb2_) ^ (((unsigned)(tr0_ & 7)) << 4)) >> 1));                  \
    const short8 a0l = *(const short8*)(AL + tr0_ * 192 +                            \
        ((((unsigned)cb2_) ^ (((unsigned)(tr0_ & 7)) << 4)) >> 1));                  \
    const short8 a1h = *(const short8*)(AH + tr1_ * 192 +                            \
        ((((unsigned)cb2_) ^ (((unsigned)(tr1_ & 7)) << 4)) >> 1));                  \
    const short8 a1l = *(const short8*)(AL + tr1_ * 192 +                            \
        ((((unsigned)cb2_) ^ (((unsigned)(tr1_ & 7)) << 4)) >> 1));                  \
    acc[0][0] = __builtin_amdgcn_mfma_f32_16x16x32_bf16(a0h, BH[0], acc[0][0], 0,0,0); \
    acc[0][1] = __builtin_amdgcn_mfma_f32_16x16x32_bf16(a0h, BH[1], acc[0][1], 0,0,0); \
    acc[0][2] = __builtin_amdgcn_mfma_f32_16x16x32_bf16(a0h, BH[2], acc[0][2], 0,0,0); \
    acc[1][0] = __builtin_amdgcn_mfma_f32_16x16x32_bf16(a1h, BH[0], acc[1][0], 0,0,0); \
    acc[1][1] = __builtin_amdgcn_mfma_f32_16x16x32_bf16(a1h, BH[1], acc[1][1], 0,0,0); \
    acc[1][2] = __builtin_amdgcn_mfma_f32_16x16x32_bf16(a1h, BH[2], acc[1][2], 0,0,0); \
    acc[0][0] = __builtin_amdgcn_mfma_f32_16x16x32_bf16(a0l, BH[0], acc[0][0], 0,0,0); \
    acc[0][1] = __builtin_amdgcn_mfma_f32_16x16x32_bf16(a0l, BH[1], acc[0][1], 0,0,0); \
    acc[0][2] = __builtin_amdgcn_mfma_f32_16x16x32_bf16(a0l, BH[2], acc[0][2], 0,0,0); \
    acc[1][0] = __builtin_amdgcn_mfma_f32_16x16x32_bf16(a1l, BH[0], acc[1][0], 0,0,0); \
    acc[1][1] = __builtin_amdgcn_mfma_f32_16x16x32_bf16(a1l, BH[1], acc[1][1], 0,0,0); \
    acc[1][2] = __builtin_amdgcn_mfma_f32_16x16x32_bf16(a1l, BH[2], acc[1][2], 0,0,0); \
    acc[0][0] = __builtin_amdgcn_mfma_f32_16x16x32_bf16(a0h, BL[0], acc[0][0], 0,0,0); \
    acc[0][1] = __builtin_amdgcn_mfma_f32_16x16x32_bf16(a0h, BL[1], acc[0][1], 0,0,0); \
    acc[0][2] = __builtin_amdgcn_mfma_f32_16x16x32_bf16(a0h, BL[2], acc[0][2], 0,0,0); \
    acc[1][0] = __builtin_amdgcn_mfma_f32_16x16x32_bf16(a1h, BL[0], acc[1][0], 0,0,0); \
    acc[1][1] = __builtin_amdgcn_mfma_f32_16x16x32_bf16(a1h, BL[1], acc[1][1], 0,0,0); \
    acc[1][2] = __builtin_amdgcn_mfma_f32_16x16x32_bf16(a1h, BL[2], acc[1][2], 0,0,0); \
} while (0)

#define KLOOP() do {                                                                 \
    short8 b0h[3], b0l[3], b1h[3], b1l[3];                                           \
    LDB(0, b0h, b0l);                                                                \
    _Pragma("unroll")                                                                \
    for (int ch = 0; ch < 18; ++ch) {                                                \
        if ((ch & 1) == 0) { if (ch < 17) LDB(ch + 1, b1h, b1l); CMP(ch, b0h, b0l); }\
        else               { if (ch < 17) LDB(ch + 1, b0h, b0l); CMP(ch, b1h, b1l); }\
    }                                                                                \
} while (0)

__global__ __launch_bounds__(256, 1)
void dngpu_persist(unsigned* __restrict__ mem0, unsigned* __restrict__ mem1,
                   unsigned* __restrict__ rm, unsigned* __restrict__ gateb,
                   const unsigned short* __restrict__ W2H,
                   const unsigned short* __restrict__ W2L,
                   const float* __restrict__ b_r, const float* __restrict__ b_g,
                   const float* __restrict__ b_c,
                   float* __restrict__ outF, unsigned* __restrict__ flags)
{
    __shared__ __align__(16) unsigned short AH[34 * 192];
    __shared__ __align__(16) unsigned short AL[34 * 192];

    const int bid = blockIdx.x;
    const int tid = threadIdx.x;
    const int lane = tid & 63, wid = tid >> 6;
    const int lrow = lane & 15, ksl = lane >> 4;
    const int s  = bid >> 1;           // strip (32 rows)
    const int n0 = s * 32;
    const int cv = bid & 1;            // phase1: conv (0=reset,1=gate); phase2: col half
    unsigned ep = 0;

    for (int t = 0; t < 128; ++t) {
        const unsigned* cur = (t & 1) ? mem1 : mem0;
        unsigned* nxt = (t & 1) ? mem0 : mem1;

        // ================= phase 1: r/g conv =================
        STAGE(cur);
        __syncthreads();
        {
            const unsigned short* WH = W2H + (size_t)cv * 110592;
            const unsigned short* WL = W2L + (size_t)cv * 110592;
            const int c0 = 48 * wid;
            const int bc0 = (ksl * 192 + c0 + lrow) * 8;
            const int bc1 = bc0 + 16 * 8;
            const int bc2 = bc0 + 32 * 8;
            f32x4 acc[2][3] = {};
            KLOOP();
            #pragma unroll
            for (int j = 0; j < 3; ++j) {
                const int col = c0 + 16 * j + lrow;
                if (cv == 0) {
                    const float br = b_r[col];
                    #pragma unroll
                    for (int mr = 0; mr < 2; ++mr) {
                        #pragma unroll
                        for (int r = 0; r < 4; ++r) {
                            const int row = n0 + 16 * mr + ksl * 4 + r;
                            const int tr  = 16 * mr + ksl * 4 + r + 1;
                            const unsigned sb = ((unsigned)(col * 2)) ^ (((unsigned)(tr & 7)) << 4);
                            const float m = bf2f(AH[tr * 192 + (sb >> 1)]) +
                                            bf2f(AL[tr * 192 + (sb >> 1)]);
                            const float rr = sigmoid_f(acc[mr][j][r] + br);
                            __hip_atomic_store(&rm[(size_t)row * 192 + col], packhl(rr * m),
                                               __ATOMIC_RELAXED, __HIP_MEMORY_SCOPE_AGENT);
                        }
                    }
                } else {
                    const float bg = b_g[col];
                    #pragma unroll
                    for (int mr = 0; mr < 2; ++mr) {
                        #pragma unroll
                        for (int r = 0; r < 4; ++r) {
                            const int row = n0 + 16 * mr + ksl * 4 + r;
                            const float g = sigmoid_f(acc[mr][j][r] + bg);
                            __hip_atomic_store(&gateb[(size_t)row * 192 + col],
                                               __float_as_uint(g),
                                               __ATOMIC_RELAXED, __HIP_MEMORY_SCOPE_AGENT);
                        }
                    }
                }
            }
        }
        gridbar(flags, bid, tid, ++ep);

        // ================= phase 2: cand conv + gating =================
        STAGE(rm);
        __syncthreads();
        if (wid < 2) {
            const unsigned short* WH = W2H + (size_t)2 * 110592;
            const unsigned short* WL = W2L + (size_t)2 * 110592;
            const int c0 = 96 * cv + 48 * wid;
            const int bc0 = (ksl * 192 + c0 + lrow) * 8;
            const int bc1 = bc0 + 16 * 8;
            const int bc2 = bc0 + 32 * 8;
            f32x4 acc[2][3] = {};
            KLOOP();
            #pragma unroll
            for (int j = 0; j < 3; ++j) {
                const int col = c0 + 16 * j + lrow;
                const float bcv = b_c[col];
                #pragma unroll
                for (int mr = 0; mr < 2; ++mr) {
                    #pragma unroll
                    for (int r = 0; r < 4; ++r) {
                        const int row = n0 + 16 * mr + ksl * 4 + r;
                        const size_t idx = (size_t)row * 192 + col;
                        const float cand = tanh_f(acc[mr][j][r] + bcv);
                        const float g = __uint_as_float(__hip_atomic_load(
                            &gateb[idx], __ATOMIC_RELAXED, __HIP_MEMORY_SCOPE_AGENT));
                        float sh = 0.0f;
                        if (row & 127) {
                            unsigned mv = __hip_atomic_load(&((unsigned*)cur)[idx - 192],
                                            __ATOMIC_RELAXED, __HIP_MEMORY_SCOPE_AGENT);
                            sh = bf2f((unsigned short)(mv & 0xFFFFu)) +
                                 bf2f((unsigned short)(mv >> 16));
                        }
                        const float o = g * sh + (1.0f - g) * cand;
                        if (t == 127) outF[idx] = o;
                        else __hip_atomic_store(&nxt[idx], packhl(o),
                                                __ATOMIC_RELAXED, __HIP_MEMORY_SCOPE_AGENT);
                    }
                }
            }
        }
        gridbar(flags, bid, tid, ++ep);
    }
}

extern "C" void kernel_launch(void* const* d_in, const int* in_sizes, int n_in,
                              void* d_out, int out_size, void* d_ws, size_t ws_size,
                              hipStream_t stream)
{
    (void)in_sizes; (void)n_in; (void)out_size; (void)ws_size;
    const float* x   = (const float*)d_in[0];
    const float* w_r = (const float*)d_in[1];
    const float* b_r = (const float*)d_in[2];
    const float* w_g = (const float*)d_in[3];
    const float* b_g = (const float*)d_in[4];
    const float* w_c = (const float*)d_in[5];
    const float* b_c = (const float*)d_in[6];
    float* out = (float*)d_out;

    const size_t NC = (size_t)NCEL;
    unsigned* mem0 = (unsigned*)d_ws;
    unsigned* mem1 = mem0 + NC;
    unsigned* rm   = mem1 + NC;
    unsigned* gate = rm + NC;
    unsigned short* W2H = (unsigned short*)(gate + NC);
    unsigned short* W2L = W2H + (size_t)WELEM;
    unsigned* flags = (unsigned*)(W2L + (size_t)WELEM);

    hipMemsetAsync(flags, 0, 1024, stream);
    prep_x<<<dim3(3072), dim3(256), 0, stream>>>(x, mem0);
    prep_w<<<dim3((WELEM + 255) / 256), dim3(256), 0, stream>>>(w_r, w_g, w_c, W2H, W2L);
    dngpu_persist<<<dim3(256), dim3(256), 0, stream>>>(
        mem0, mem1, rm, gate, W2H, W2L, b_r, b_g, b_c, out, flags);
}

// Round 4
// 4269.155 us; speedup vs baseline: 2.5167x; 2.5167x over previous
//
#include <hip/hip_runtime.h>

typedef __attribute__((ext_vector_type(8))) short short8;
typedef __attribute__((ext_vector_type(4))) float f32x4;

#define NROWS 4096     // B*L = 32*128
#define CC    192
#define NCEL  (NROWS * CC)

#define W1ELEM (4 * 18 * 96 * 32)   // 221184 (r|g concat, grouped)
#define W2ELEM (2 * 18 * 96 * 32)   // 110592 (cand)

typedef const __attribute__((address_space(1))) void as1_void;
typedef __attribute__((address_space(3))) void as3_void;
#define GLD_LDS16(G, L) __builtin_amdgcn_global_load_lds((as1_void*)(G), (as3_void*)(L), 16, 0, 0)

// ---------- numerics helpers ----------
__device__ __forceinline__ unsigned short f2bf(float x) {
    union { float f; unsigned int u; } v; v.f = x;
    unsigned int r = v.u + 0x7fffu + ((v.u >> 16) & 1u);   // RNE
    return (unsigned short)(r >> 16);
}
__device__ __forceinline__ float bf2f(unsigned short h) {
    union { unsigned int u; float f; } v; v.u = ((unsigned int)h) << 16;
    return v.f;
}
__device__ __forceinline__ unsigned packhl(float x) {
    unsigned short h = f2bf(x);
    unsigned short l = f2bf(x - bf2f(h));
    return (unsigned)h | ((unsigned)l << 16);
}
__device__ __forceinline__ float unpackhl(unsigned v) {
    return bf2f((unsigned short)(v & 0xFFFFu)) + bf2f((unsigned short)(v >> 16));
}
__device__ __forceinline__ float sigmoid_f(float x) {
    return 1.0f / (1.0f + __expf(-x));
}
// poly for small |x| (abs err ~2e-10), exp form above (err decays before output)
__device__ __forceinline__ float tanh_f(float x) {
    float ax = fabsf(x);
    if (ax < 0.0625f) {
        float x2 = x * x;
        return x * fmaf(x2, fmaf(x2, 0.13333333f, -0.33333333f), 1.0f);
    }
    float e = __expf(2.0f * fminf(ax, 20.0f));
    float t = (e - 1.0f) / (e + 1.0f);
    return x < 0.0f ? -t : t;
}

// ---------- prep ----------
__global__ void prep_x(const float* __restrict__ x, unsigned* __restrict__ memHL) {
    int i = blockIdx.x * 256 + threadIdx.x;
    if (i < NCEL) memHL[i] = packhl(x[i]);
}

// W layout: [grp][ch 18][col 96][kc 32], H/L planes. k1: grp0,1=r cols 0/96; grp2,3=g.
// chunk ch: kk=ch/6, ci0=(ch%6)*32; element (col,kc) = W(c = grpbase+col, k = kk*192+ci0+kc)
__global__ void prep_w(const float* __restrict__ wr, const float* __restrict__ wg,
                       const float* __restrict__ wc,
                       unsigned short* __restrict__ W1H, unsigned short* __restrict__ W1L,
                       unsigned short* __restrict__ W2H, unsigned short* __restrict__ W2L) {
    int i = blockIdx.x * 256 + threadIdx.x;
    if (i >= W1ELEM + W2ELEM) return;
    const float* w; int grp, rem, cbase; unsigned short *H, *L; int dst;
    if (i < W1ELEM) {
        grp = i / 55296; rem = i % 55296;
        w = (grp >> 1) ? wg : wr;
        cbase = (grp & 1) * 96;
        H = W1H; L = W1L; dst = i;
    } else {
        int ii = i - W1ELEM;
        grp = ii / 55296; rem = ii % 55296;
        w = wc; cbase = grp * 96;
        H = W2H; L = W2L; dst = ii;
    }
    int ch = rem / 3072, r2 = rem % 3072, col = r2 / 32, kc = r2 % 32;
    int kk = ch / 6, ci = (ch % 6) * 32 + kc;
    int c = cbase + col;
    float v = w[(size_t)(kk * 192 + ci) * 192 + c];
    unsigned short h = f2bf(v);
    H[dst] = h; L[dst] = f2bf(v - bf2f(h));
}

// ---- A stage: 34 rows (n0-1..n0+32) of packed h|l<<16, swizzled into AH/AL
#define ASTAGE(SRC, NT, NIT) do {                                                    \
    _Pragma("unroll")                                                                \
    for (int it_ = 0; it_ < (NIT); ++it_) {                                          \
        int q_ = it_ * (NT) + tid;                                                   \
        if (q_ < 34 * 96) {                                                          \
            int row_ = q_ / 96, u_ = q_ - row_ * 96;                                 \
            int gr_ = n0 - 1 + row_;                                                 \
            unsigned long long v_ = 0ull;                                            \
            if (gr_ >= 0 && ((gr_ >> 7) == (n0 >> 7)))                               \
                v_ = *(const unsigned long long*)((SRC) + (size_t)gr_ * 192 + u_ * 2);\
            unsigned lo_ = (unsigned)v_, hi_ = (unsigned)(v_ >> 32);                 \
            unsigned byt_ = ((unsigned)(u_ * 4)) ^ (((unsigned)(row_ & 7)) << 4);    \
            unsigned wdx_ = (((unsigned)row_) * 384 + byt_) >> 2;                    \
            ((unsigned*)AH)[wdx_] = (lo_ & 0xFFFFu) | (hi_ << 16);                   \
            ((unsigned*)AL)[wdx_] = (lo_ >> 16) | (hi_ & 0xFFFF0000u);               \
        }                                                                            \
    }                                                                                \
} while (0)

// ================= k1: reset+gate conv =================
// grid (128 strips, 4 grps of 96 concat cols), 128 thr = 2 waves of 32x48 (m2n3)
__global__ __launch_bounds__(128)
void k1_rg(const unsigned* __restrict__ mem,
           const unsigned short* __restrict__ W1H, const unsigned short* __restrict__ W1L,
           const float* __restrict__ b_r, const float* __restrict__ b_g,
           float* __restrict__ gate, unsigned* __restrict__ rm)
{
    __shared__ __align__(16) unsigned short AH[34 * 192];
    __shared__ __align__(16) unsigned short AL[34 * 192];
    __shared__ __align__(16) unsigned short WB[2][2][96 * 32];  // [buf][hl][col][kc]

    const int strip = blockIdx.x, grp = blockIdx.y;
    const int n0 = strip * 32;
    const int tid = threadIdx.x;

    ASTAGE(mem, 128, 26);

    const int lane = tid & 63, w = tid >> 6;
    const int lrow = lane & 15, lkg = lane >> 4;

    const unsigned short* Wp = (w ? W1L : W1H) + (size_t)grp * 55296;  // wave w stages plane w
    #define STAGEB1(BUF, CH) do {                                                    \
        const unsigned short* s_ = Wp + (CH) * 3072 + lane * 8;                      \
        unsigned short* d_ = &WB[BUF][w][0];                                         \
        _Pragma("unroll")                                                            \
        for (int j_ = 0; j_ < 6; ++j_)                                               \
            GLD_LDS16(s_ + j_ * 512, d_ + j_ * 512);                                 \
    } while (0)

    STAGEB1(0, 0);
    __syncthreads();

    f32x4 acc[2][3] = {};
    int buf = 0;
    #pragma unroll 2
    for (int ch = 0; ch < 18; ++ch) {
        if (ch < 17) STAGEB1(buf ^ 1, ch + 1);
        const int kk = ch / 6, cib = (ch % 6) * 32;
        short8 aH[2], aL[2];
        #pragma unroll
        for (int mt = 0; mt < 2; ++mt) {
            const int slot = 16 * mt + lrow + kk;
            const unsigned byt = ((unsigned)((cib + lkg * 8) * 2)) ^ (((unsigned)(slot & 7)) << 4);
            const int off = slot * 192 + (byt >> 1);
            aH[mt] = *(const short8*)(AH + off);
            aL[mt] = *(const short8*)(AL + off);
        }
        short8 bH[3], bL[3];
        #pragma unroll
        for (int j = 0; j < 3; ++j) {
            const int c = w * 48 + j * 16 + lrow;
            bH[j] = *(const short8*)(&WB[buf][0][c * 32 + lkg * 8]);
            bL[j] = *(const short8*)(&WB[buf][1][c * 32 + lkg * 8]);
        }
        #pragma unroll
        for (int mt = 0; mt < 2; ++mt)
            #pragma unroll
            for (int j = 0; j < 3; ++j) {
                acc[mt][j] = __builtin_amdgcn_mfma_f32_16x16x32_bf16(aH[mt], bH[j], acc[mt][j], 0, 0, 0);
                acc[mt][j] = __builtin_amdgcn_mfma_f32_16x16x32_bf16(aL[mt], bH[j], acc[mt][j], 0, 0, 0);
                acc[mt][j] = __builtin_amdgcn_mfma_f32_16x16x32_bf16(aH[mt], bL[j], acc[mt][j], 0, 0, 0);
            }
        __syncthreads();
        buf ^= 1;
    }

    const int conv = grp >> 1;
    const int c0g = (grp & 1) * 96 + w * 48;
    #pragma unroll
    for (int j = 0; j < 3; ++j) {
        const int c = c0g + 16 * j + lrow;
        const float bb = conv ? b_g[c] : b_r[c];
        #pragma unroll
        for (int mt = 0; mt < 2; ++mt) {
            #pragma unroll
            for (int r = 0; r < 4; ++r) {
                const int row = n0 + 16 * mt + lkg * 4 + r;
                const size_t idx = (size_t)row * 192 + c;
                const float s = sigmoid_f(acc[mt][j][r] + bb);
                if (conv == 0) {
                    const float m = unpackhl(mem[idx]);
                    rm[idx] = packhl(s * m);
                } else {
                    gate[idx] = s;
                }
            }
        }
    }
}

// ================= k2: cand conv + gating =================
// grid (128 strips, 2 grps of 96), 256 thr = 4 waves of 16x48 (m1n3)
__global__ __launch_bounds__(256)
void k2_c(const unsigned* __restrict__ rm,
          const unsigned short* __restrict__ W2H, const unsigned short* __restrict__ W2L,
          const float* __restrict__ b_c, const float* __restrict__ gate,
          const unsigned* __restrict__ mem, unsigned* __restrict__ nxt,
          float* __restrict__ outF, int last)
{
    __shared__ __align__(16) unsigned short AH[34 * 192];
    __shared__ __align__(16) unsigned short AL[34 * 192];
    __shared__ __align__(16) unsigned short WB[2][2][96 * 32];

    const int strip = blockIdx.x, grp = blockIdx.y;
    const int n0 = strip * 32;
    const int tid = threadIdx.x;

    ASTAGE(rm, 256, 13);

    const int lane = tid & 63, w = tid >> 6;
    const int lrow = lane & 15, lkg = lane >> 4;
    const int mtw = w >> 1, ng = w & 1;

    const unsigned short* WpH = W2H + (size_t)grp * 55296;
    const unsigned short* WpL = W2L + (size_t)grp * 55296;
    #define STAGEB2(BUF, CH) do {                                                    \
        _Pragma("unroll")                                                            \
        for (int j_ = 0; j_ < 3; ++j_) {                                             \
            const int id_ = w * 3 + j_;                                              \
            const int pl_ = id_ / 6, sg_ = id_ % 6;                                  \
            const unsigned short* s_ = (pl_ ? WpL : WpH) + (CH) * 3072 + sg_ * 512 + lane * 8; \
            GLD_LDS16(s_, &WB[BUF][pl_][sg_ * 512]);                                 \
        }                                                                            \
    } while (0)

    STAGEB2(0, 0);
    __syncthreads();

    f32x4 acc[3] = {};
    int buf = 0;
    #pragma unroll 2
    for (int ch = 0; ch < 18; ++ch) {
        if (ch < 17) STAGEB2(buf ^ 1, ch + 1);
        const int kk = ch / 6, cib = (ch % 6) * 32;
        const int slot = 16 * mtw + lrow + kk;
        const unsigned byt = ((unsigned)((cib + lkg * 8) * 2)) ^ (((unsigned)(slot & 7)) << 4);
        const int off = slot * 192 + (byt >> 1);
        const short8 aH = *(const short8*)(AH + off);
        const short8 aL = *(const short8*)(AL + off);
        short8 bH[3], bL[3];
        #pragma unroll
        for (int j = 0; j < 3; ++j) {
            const int c = ng * 48 + j * 16 + lrow;
            bH[j] = *(const short8*)(&WB[buf][0][c * 32 + lkg * 8]);
            bL[j] = *(const short8*)(&WB[buf][1][c * 32 + lkg * 8]);
        }
        #pragma unroll
        for (int j = 0; j < 3; ++j) {
            acc[j] = __builtin_amdgcn_mfma_f32_16x16x32_bf16(aH, bH[j], acc[j], 0, 0, 0);
            acc[j] = __builtin_amdgcn_mfma_f32_16x16x32_bf16(aL, bH[j], acc[j], 0, 0, 0);
            acc[j] = __builtin_amdgcn_mfma_f32_16x16x32_bf16(aH, bL[j], acc[j], 0, 0, 0);
        }
        __syncthreads();
        buf ^= 1;
    }

    const int c0g = grp * 96 + ng * 48;
    #pragma unroll
    for (int j = 0; j < 3; ++j) {
        const int c = c0g + 16 * j + lrow;
        const float bcv = b_c[c];
        #pragma unroll
        for (int r = 0; r < 4; ++r) {
            const int row = n0 + 16 * mtw + lkg * 4 + r;
            const size_t idx = (size_t)row * 192 + c;
            const float cand = tanh_f(acc[j][r] + bcv);
            const float g = gate[idx];
            float sh = 0.0f;
            if (row & 127) sh = unpackhl(mem[idx - 192]);
            const float o = g * sh + (1.0f - g) * cand;
            if (last) outF[idx] = o;
            else      nxt[idx] = packhl(o);
        }
    }
}

extern "C" void kernel_launch(void* const* d_in, const int* in_sizes, int n_in,
                              void* d_out, int out_size, void* d_ws, size_t ws_size,
                              hipStream_t stream)
{
    (void)in_sizes; (void)n_in; (void)out_size; (void)ws_size;
    const float* x   = (const float*)d_in[0];
    const float* w_r = (const float*)d_in[1];
    const float* b_r = (const float*)d_in[2];
    const float* w_g = (const float*)d_in[3];
    const float* b_g = (const float*)d_in[4];
    const float* w_c = (const float*)d_in[5];
    const float* b_c = (const float*)d_in[6];
    float* out = (float*)d_out;

    const size_t NC = (size_t)NCEL;
    unsigned* mem0 = (unsigned*)d_ws;
    unsigned* mem1 = mem0 + NC;
    unsigned* rm   = mem1 + NC;
    float*    gate = (float*)(rm + NC);
    unsigned short* W1H = (unsigned short*)(gate + NC);
    unsigned short* W1L = W1H + (size_t)W1ELEM;
    unsigned short* W2H = W1L + (size_t)W1ELEM;
    unsigned short* W2L = W2H + (size_t)W2ELEM;

    prep_x<<<dim3((NCEL + 255) / 256), dim3(256), 0, stream>>>(x, mem0);
    prep_w<<<dim3((W1ELEM + W2ELEM + 255) / 256), dim3(256), 0, stream>>>(
        w_r, w_g, w_c, W1H, W1L, W2H, W2L);

    for (int t = 0; t < 128; ++t) {
        const unsigned* cur = (t & 1) ? mem1 : mem0;
        unsigned* nxt = (t & 1) ? mem0 : mem1;
        k1_rg<<<dim3(128, 4), dim3(128), 0, stream>>>(cur, W1H, W1L, b_r, b_g, gate, rm);
        k2_c<<<dim3(128, 2), dim3(256), 0, stream>>>(rm, W2H, W2L, b_c, gate,
                                                     cur, nxt, out, t == 127);
    }
}

// Round 6
// 3798.190 us; speedup vs baseline: 2.8287x; 1.1240x over previous
//
#include <hip/hip_runtime.h>

typedef __attribute__((ext_vector_type(8)))  short short8;
typedef __attribute__((ext_vector_type(4)))  float f32x4;
typedef __attribute__((ext_vector_type(16))) float f32x16;

#define NROWS 4096     // B*L = 32*128
#define CC    192
#define NCEL  (NROWS * CC)

// W layout: [grp 6][ch 18][pl 2][p 384] 16B-blocks; grp = conv*2 + colhalf
// p = col*4 + slotp, slotp = (slot+col)&3, block holds k = ci0(ch) + slot*8 + e
#define WTELEM (6 * 18 * 2 * 384 * 8)   // 663552 ushorts

typedef const __attribute__((address_space(1))) void as1_void;
typedef __attribute__((address_space(3))) void as3_void;
#define GLD_LDS16(G, L) __builtin_amdgcn_global_load_lds((as1_void*)(G), (as3_void*)(L), 16, 0, 0)

// ---------- numerics helpers ----------
__device__ __forceinline__ unsigned short f2bf(float x) {
    union { float f; unsigned int u; } v; v.f = x;
    unsigned int r = v.u + 0x7fffu + ((v.u >> 16) & 1u);   // RNE
    return (unsigned short)(r >> 16);
}
__device__ __forceinline__ float bf2f(unsigned short h) {
    union { unsigned int u; float f; } v; v.u = ((unsigned int)h) << 16;
    return v.f;
}
__device__ __forceinline__ unsigned packhl(float x) {
    unsigned short h = f2bf(x);
    unsigned short l = f2bf(x - bf2f(h));
    return (unsigned)h | ((unsigned)l << 16);
}
__device__ __forceinline__ float unpackhl(unsigned v) {
    return bf2f((unsigned short)(v & 0xFFFFu)) + bf2f((unsigned short)(v >> 16));
}
__device__ __forceinline__ float sigmoid_f(float x) {
    return 1.0f / (1.0f + __expf(-x));
}
// poly for small |x| (abs err ~2e-10), exp form above (err decays before output)
__device__ __forceinline__ float tanh_f(float x) {
    float ax = fabsf(x);
    if (ax < 0.0625f) {
        float x2 = x * x;
        return x * fmaf(x2, fmaf(x2, 0.13333333f, -0.33333333f), 1.0f);
    }
    float e = __expf(2.0f * fminf(ax, 20.0f));
    float t = (e - 1.0f) / (e + 1.0f);
    return x < 0.0f ? -t : t;
}

// ---------- prep ----------
__global__ void prep_x(const float* __restrict__ x, unsigned* __restrict__ memHL) {
    int i = blockIdx.x * 256 + threadIdx.x;
    if (i < NCEL) memHL[i] = packhl(x[i]);
}

__global__ void prep_w(const float* __restrict__ wr, const float* __restrict__ wg,
                       const float* __restrict__ wc, unsigned short* __restrict__ Wt) {
    int o = blockIdx.x * 256 + threadIdx.x;
    if (o >= WTELEM) return;
    int e  = o & 7;
    int b  = o >> 3;                 // 16B-block index
    int p  = b % 384;
    int pl = (b / 384) % 2;
    int ch = (b / 768) % 18;
    int grp = b / (768 * 18);
    int col = p >> 2;
    int slotp = p & 3;
    int slot = (slotp - col) & 3;
    int kk = ch / 6;
    int ci = (ch % 6) * 32 + slot * 8 + e;
    int conv = grp >> 1;
    int cglob = (grp & 1) * 96 + col;
    const float* w = (conv == 0) ? wr : ((conv == 1) ? wg : wc);
    float v = w[(size_t)(kk * 192 + ci) * 192 + cglob];
    unsigned short h = f2bf(v);
    Wt[o] = pl ? f2bf(v - bf2f(h)) : h;
}

// ---- A stage: 34 rows (n0-1..n0+32) of packed h|l<<16, swizzled into AH/AL
#define ASTAGE(SRC, NT, NIT) do {                                                    \
    _Pragma("unroll")                                                                \
    for (int it_ = 0; it_ < (NIT); ++it_) {                                          \
        int q_ = it_ * (NT) + tid;                                                   \
        if (q_ < 34 * 96) {                                                          \
            int row_ = q_ / 96, u_ = q_ - row_ * 96;                                 \
            int gr_ = n0 - 1 + row_;                                                 \
            unsigned long long v_ = 0ull;                                            \
            if (gr_ >= 0 && ((gr_ >> 7) == (n0 >> 7)))                               \
                v_ = *(const unsigned long long*)((SRC) + (size_t)gr_ * 192 + u_ * 2);\
            unsigned lo_ = (unsigned)v_, hi_ = (unsigned)(v_ >> 32);                 \
            unsigned byt_ = ((unsigned)(u_ * 4)) ^ (((unsigned)(row_ & 7)) << 4);    \
            unsigned wdx_ = (((unsigned)row_) * 384 + byt_) >> 2;                    \
            ((unsigned*)AH)[wdx_] = (lo_ & 0xFFFFu) | (hi_ << 16);                   \
            ((unsigned*)AL)[wdx_] = (lo_ >> 16) | (hi_ & 0xFFFF0000u);               \
        }                                                                            \
    }                                                                                \
} while (0)

// B staging: one chunk = [pl 2][p 384] 16B blocks = 12KB, linear gld_lds
#define STAGEB(BUF, CH, NT) do {                                                     \
    const unsigned short* s_ = Wsec + (size_t)(CH) * 6144;                           \
    _Pragma("unroll")                                                                \
    for (int it_ = 0; it_ < 768 / (NT); ++it_) {                                     \
        int q_ = it_ * (NT) + tid;                                                   \
        GLD_LDS16(s_ + q_ * 8, &WB[BUF][q_ * 8]);                                    \
    }                                                                                \
} while (0)

// ================= k1: reset | gate conv (32x32x16 MFMA) =================
// grid (128 strips, 4 = conv*2+half), 192 thr = 3 waves, wave = 32r x 32c
__global__ __launch_bounds__(192)
void k1_rg(const unsigned* __restrict__ mem,
           const unsigned short* __restrict__ Wt,
           const float* __restrict__ b_r, const float* __restrict__ b_g,
           float* __restrict__ gate, unsigned* __restrict__ rm)
{
    __shared__ __align__(16) unsigned short AH[34 * 192];
    __shared__ __align__(16) unsigned short AL[34 * 192];
    __shared__ __align__(16) unsigned short WB[2][6144];

    const int strip = blockIdx.x, grp = blockIdx.y;   // grp = conv*2 + half
    const int n0 = strip * 32;
    const int tid = threadIdx.x;

    ASTAGE(mem, 192, 17);

    const int lane = tid & 63, w = tid >> 6;
    const int lr32 = lane & 31, khalf = lane >> 5;
    const int col96 = w * 32 + lr32;

    const unsigned short* Wsec = Wt + (size_t)grp * 18 * 6144;

    STAGEB(0, 0, 192);
    __syncthreads();

    f32x16 acc = {};
    int buf = 0;
    #pragma unroll 2
    for (int ch = 0; ch < 18; ++ch) {
        if (ch < 17) STAGEB(buf ^ 1, ch + 1, 192);
        const int kk = ch / 6, ci0 = (ch % 6) * 32;
        const int tr = lr32 + kk;          // slot of input row (m-1+kk): FIXED (was +1 extra)
        short8 aH[2], aL[2], bH[2], bL[2];
        #pragma unroll
        for (int ks = 0; ks < 2; ++ks) {
            const int slot = ks * 2 + khalf;
            const unsigned byt = ((unsigned)((ci0 + slot * 8) * 2)) ^ (((unsigned)(tr & 7)) << 4);
            const int aoff = tr * 192 + (byt >> 1);
            aH[ks] = *(const short8*)(AH + aoff);
            aL[ks] = *(const short8*)(AL + aoff);
            const int boff = col96 * 32 + ((slot + col96) & 3) * 8;
            bH[ks] = *(const short8*)(&WB[buf][boff]);
            bL[ks] = *(const short8*)(&WB[buf][3072 + boff]);
        }
        #pragma unroll
        for (int ks = 0; ks < 2; ++ks) {
            acc = __builtin_amdgcn_mfma_f32_32x32x16_bf16(aH[ks], bH[ks], acc, 0, 0, 0);
            acc = __builtin_amdgcn_mfma_f32_32x32x16_bf16(aL[ks], bH[ks], acc, 0, 0, 0);
            acc = __builtin_amdgcn_mfma_f32_32x32x16_bf16(aH[ks], bL[ks], acc, 0, 0, 0);
        }
        __syncthreads();
        buf ^= 1;
    }

    const int conv = grp >> 1;
    const int chan = (grp & 1) * 96 + col96;
    const float bb = conv ? b_g[chan] : b_r[chan];
    #pragma unroll
    for (int r = 0; r < 16; ++r) {
        const int rl = (r & 3) + 8 * (r >> 2) + 4 * khalf;    // 32x32 C/D row map
        const int row = n0 + rl;
        const size_t idx = (size_t)row * 192 + chan;
        const float s = sigmoid_f(acc[r] + bb);
        if (conv == 0) {
            const int tr = rl + 1;
            const unsigned sb = ((unsigned)(chan * 2)) ^ (((unsigned)(tr & 7)) << 4);
            const float m = bf2f(AH[tr * 192 + (sb >> 1)]) + bf2f(AL[tr * 192 + (sb >> 1)]);
            rm[idx] = packhl(s * m);
        } else {
            gate[idx] = s;
        }
    }
}

// ================= k2: cand conv + gating (16x16x32 MFMA) =================
// grid (128 strips, 2 halves), 256 thr = 4 waves, wave = 16r x 48c
__global__ __launch_bounds__(256)
void k2_c(const unsigned* __restrict__ rm,
          const unsigned short* __restrict__ Wt,
          const float* __restrict__ b_c, const float* __restrict__ gate,
          const unsigned* __restrict__ mem, unsigned* __restrict__ nxt,
          float* __restrict__ outF, int last)
{
    __shared__ __align__(16) unsigned short AH[34 * 192];
    __shared__ __align__(16) unsigned short AL[34 * 192];
    __shared__ __align__(16) unsigned short WB[2][6144];

    const int strip = blockIdx.x, half = blockIdx.y;
    const int n0 = strip * 32;
    const int tid = threadIdx.x;

    ASTAGE(rm, 256, 13);

    const int lane = tid & 63, w = tid >> 6;
    const int lrow = lane & 15, lkg = lane >> 4;
    const int mtw = w >> 1, ng = w & 1;

    const unsigned short* Wsec = Wt + (size_t)(4 + half) * 18 * 6144;

    STAGEB(0, 0, 256);
    __syncthreads();

    f32x4 acc[3] = {};
    int buf = 0;
    #pragma unroll 2
    for (int ch = 0; ch < 18; ++ch) {
        if (ch < 17) STAGEB(buf ^ 1, ch + 1, 256);
        const int kk = ch / 6, ci0 = (ch % 6) * 32;
        const int tr = 16 * mtw + lrow + kk;
        const unsigned byt = ((unsigned)((ci0 + lkg * 8) * 2)) ^ (((unsigned)(tr & 7)) << 4);
        const int aoff = tr * 192 + (byt >> 1);
        const short8 aH = *(const short8*)(AH + aoff);
        const short8 aL = *(const short8*)(AL + aoff);
        short8 bH[3], bL[3];
        #pragma unroll
        for (int j = 0; j < 3; ++j) {
            const int c96 = ng * 48 + j * 16 + lrow;
            const int boff = c96 * 32 + ((lkg + c96) & 3) * 8;
            bH[j] = *(const short8*)(&WB[buf][boff]);
            bL[j] = *(const short8*)(&WB[buf][3072 + boff]);
        }
        #pragma unroll
        for (int j = 0; j < 3; ++j) {
            acc[j] = __builtin_amdgcn_mfma_f32_16x16x32_bf16(aH, bH[j], acc[j], 0, 0, 0);
            acc[j] = __builtin_amdgcn_mfma_f32_16x16x32_bf16(aL, bH[j], acc[j], 0, 0, 0);
            acc[j] = __builtin_amdgcn_mfma_f32_16x16x32_bf16(aH, bL[j], acc[j], 0, 0, 0);
        }
        __syncthreads();
        buf ^= 1;
    }

    #pragma unroll
    for (int j = 0; j < 3; ++j) {
        const int chan = half * 96 + ng * 48 + j * 16 + lrow;
        const float bcv = b_c[chan];
        #pragma unroll
        for (int r = 0; r < 4; ++r) {
            const int row = n0 + 16 * mtw + lkg * 4 + r;
            const size_t idx = (size_t)row * 192 + chan;
            const float cand = tanh_f(acc[j][r] + bcv);
            const float g = gate[idx];
            float sh = 0.0f;
            if (row & 127) sh = unpackhl(mem[idx - 192]);
            const float o = g * sh + (1.0f - g) * cand;
            if (last) outF[idx] = o;
            else      nxt[idx] = packhl(o);
        }
    }
}

extern "C" void kernel_launch(void* const* d_in, const int* in_sizes, int n_in,
                              void* d_out, int out_size, void* d_ws, size_t ws_size,
                              hipStream_t stream)
{
    (void)in_sizes; (void)n_in; (void)out_size; (void)ws_size;
    const float* x   = (const float*)d_in[0];
    const float* w_r = (const float*)d_in[1];
    const float* b_r = (const float*)d_in[2];
    const float* w_g = (const float*)d_in[3];
    const float* b_g = (const float*)d_in[4];
    const float* w_c = (const float*)d_in[5];
    const float* b_c = (const float*)d_in[6];
    float* out = (float*)d_out;

    const size_t NC = (size_t)NCEL;
    unsigned* mem0 = (unsigned*)d_ws;
    unsigned* mem1 = mem0 + NC;
    unsigned* rm   = mem1 + NC;
    float*    gate = (float*)(rm + NC);
    unsigned short* Wt = (unsigned short*)(gate + NC);

    prep_x<<<dim3((NCEL + 255) / 256), dim3(256), 0, stream>>>(x, mem0);
    prep_w<<<dim3((WTELEM + 255) / 256), dim3(256), 0, stream>>>(w_r, w_g, w_c, Wt);

    for (int t = 0; t < 128; ++t) {
        const unsigned* cur = (t & 1) ? mem1 : mem0;
        unsigned* nxt = (t & 1) ? mem0 : mem1;
        k1_rg<<<dim3(128, 4), dim3(192), 0, stream>>>(cur, Wt, b_r, b_g, gate, rm);
        k2_c<<<dim3(128, 2), dim3(256), 0, stream>>>(rm, Wt, b_c, gate,
                                                     cur, nxt, out, t == 127);
    }
}